// Round 11
// baseline (4056.360 us; speedup 1.0000x reference)
//
#include <hip/hip_runtime.h>
#include <hip/hip_bf16.h>

#define NW 256
#define NDEPTH 10
#define NS 51           // shifts per matrix: 510 WGs (= capacity at 2 WG/CU)
#define PAD 12          // stride 48B: 16B-aligned rows, bank-group 3rg%8 injective
#define PIV_EPS 1e-6f   // LDL tiny-pivot guard

// ---------------- fused forward: first fc + 10 residual blocks + last fc ----------------
__global__ __launch_bounds__(256) void forward_kernel(
    const float* __restrict__ x, const float* __restrict__ W1, const float* __restrict__ b1,
    const float* __restrict__ Wb, const float* __restrict__ bb,
    const float* __restrict__ Wl, const float* __restrict__ bl,
    float* __restrict__ out) {
  const int b = blockIdx.x;
  const int o = threadIdx.x;
  __shared__ __align__(16) float xs[784];
  __shared__ __align__(16) float ybuf[2][NW];

  for (int k = o; k < 784; k += 256) xs[k] = x[(size_t)b * 784 + k];
  __syncthreads();

  {
    const float* w1r = W1 + (size_t)o * 784;
    float s = b1[o];
    for (int k = 0; k < 784; k += 4) {
      float4 w = *(const float4*)(w1r + k);
      float4 xv = *(const float4*)(&xs[k]);
      s += w.x * xv.x + w.y * xv.y + w.z * xv.z + w.w * xv.w;
    }
    ybuf[0][o] = fmaxf(s, 0.f);
  }
  __syncthreads();

  int cur = 0;
  for (int d = 0; d < NDEPTH; ++d) {
    const float* wr = Wb + (size_t)d * NW * NW + (size_t)o * NW;
    const float* yc = ybuf[cur];
    float acc = bb[d * NW + o];
#pragma unroll 8
    for (int k = 0; k < NW; k += 4) {
      float4 w = *(const float4*)(wr + k);
      float4 yv = *(const float4*)(&yc[k]);
      acc += w.x * yv.x + w.y * yv.y + w.z * yv.z + w.w * yv.w;
    }
    float ynew = fmaxf(acc, 0.f) + yc[o];
    ybuf[cur ^ 1][o] = ynew;
    __syncthreads();
    cur ^= 1;
  }

  if (o < 10) {
    const float* wr = Wl + o * NW;
    const float* yc = ybuf[cur];
    float acc = bl[o];
    for (int k = 0; k < NW; k += 4) {
      float4 w = *(const float4*)(wr + k);
      float4 yv = *(const float4*)(&yc[k]);
      acc += w.x * yv.x + w.y * yv.y + w.z * yv.z + w.w * yv.w;
    }
    out[b * 10 + o] = acc;
  }
}

// ---------------- B = (I+W)^T (I+W) for all 10 blocks + fused max-abs-rowsum ----------------
// rsmax[mat] (uint bit-pattern of positive float) accumulates max_r sum_c |B[r][c]|
// via atomicMax; buffer must be zeroed before launch (hipMemsetAsync).
__global__ void bmat_kernel(const float* __restrict__ Wb, float* __restrict__ Ball,
                            unsigned int* __restrict__ rsmax) {
  const int blk = blockIdx.x;        // 10 * 32
  const int k   = blk >> 5;
  const int r0  = (blk & 31) << 3;   // 8 rows per block
  const int c   = threadIdx.x;       // 256
  const float* W = Wb + (size_t)k * NW * NW;
  float acc[8] = {0.f,0.f,0.f,0.f,0.f,0.f,0.f,0.f};
  for (int j = 0; j < NW; ++j) {
    const float wc = W[j * NW + c];
#pragma unroll
    for (int rr = 0; rr < 8; ++rr) acc[rr] += wc * W[j * NW + r0 + rr];
  }
  float a[8];
#pragma unroll
  for (int rr = 0; rr < 8; ++rr) {
    const int r = r0 + rr;
    const float s = acc[rr] + W[c * NW + r] + W[r * NW + c] + ((r == c) ? 1.f : 0.f);
    Ball[(size_t)k * NW * NW + r * NW + c] = s;
    a[rr] = fabsf(s);
  }
  // per-row abs sums across the 256 threads (wave shuffle + LDS combine)
  __shared__ float wsum[4][8];
#pragma unroll
  for (int off = 32; off; off >>= 1) {
#pragma unroll
    for (int rr = 0; rr < 8; ++rr) a[rr] += __shfl_down(a[rr], off);
  }
  if ((c & 63) == 0) {
#pragma unroll
    for (int rr = 0; rr < 8; ++rr) wsum[c >> 6][rr] = a[rr];
  }
  __syncthreads();
  if (c == 0) {
    float mx = 0.f;
#pragma unroll
    for (int rr = 0; rr < 8; ++rr) {
      const float s = wsum[0][rr] + wsum[1][rr] + wsum[2][rr] + wsum[3][rr];
      mx = fmaxf(mx, s);
    }
    atomicMax(&rsmax[k], __float_as_uint(mx));   // positive floats: uint order == float order
  }
}

// ---------------- LDL inertia kernel v6: rank-2, b128 LDS, 2 WG/CU target ----------------
// counts[mat*NS + s] = #negative pivots of LDL^T(B - mu_s I) = #{lambda < mu_s}.
// __launch_bounds__(1024, 8): min 8 waves/EU -> VGPR cap 64 (current use 60),
// declaring the 2-workgroups-per-CU occupancy so barrier stalls of one WG are
// covered by the other WG's VALU phases.
__global__ __launch_bounds__(1024, 8) void ldl_kernel(const float* __restrict__ Ball,
                                                      const unsigned int* __restrict__ rsmax,
                                                      int* __restrict__ counts) {
  const int s   = blockIdx.x;     // shift index 0..NS-1
  const int mat = blockIdx.y;     // 0..9
  const int t = threadIdx.x;      // 0..1023
  const int l = t & 63;
  const int w = t >> 6;              // wave 0..15
  const int rg = l & 31;             // row group: rows [8rg, 8rg+8)
  const int ch = 2 * w + (l >> 5);   // col chunk: cols [8ch, 8ch+8)
  const int r0 = rg << 3;

  __shared__ __align__(16) float vrow[2][2][32 * PAD];   // [m-parity][row k+0/k+1]

  const float h = sqrtf(__uint_as_float(rsmax[mat])) * (1.f / NS);
  const float sg = (s + 1) * h;
  const float mu = sg * sg;

  float Bf[64];   // row r0+i, col c0+j at Bf[i*8+j]
  {
    const float* src = Ball + (size_t)mat * NW * NW + (size_t)r0 * NW + (ch << 3);
#pragma unroll
    for (int i = 0; i < 8; ++i) {
      const float4 a = *(const float4*)(src + i * NW);
      const float4 b = *(const float4*)(src + i * NW + 4);
      Bf[i*8+0] = a.x; Bf[i*8+1] = a.y; Bf[i*8+2] = a.z; Bf[i*8+3] = a.w;
      Bf[i*8+4] = b.x; Bf[i*8+5] = b.y; Bf[i*8+6] = b.z; Bf[i*8+7] = b.w;
    }
  }
  // diagonal tile: subtract mu at (r0+i, c0+i)
  if (rg == ch) {
#pragma unroll
    for (int i = 0; i < 8; ++i) Bf[i*8+i] -= mu;
  }

  // initial dump: rows 0 and 1 (= columns 0,1), parity 0
  if (rg == 0) {
    float* vd0 = &vrow[0][0][ch * PAD];
    float* vd1 = &vrow[0][1][ch * PAD];
    *(float4*)&vd0[0] = make_float4(Bf[0],  Bf[1],  Bf[2],  Bf[3]);
    *(float4*)&vd0[4] = make_float4(Bf[4],  Bf[5],  Bf[6],  Bf[7]);
    *(float4*)&vd1[0] = make_float4(Bf[8],  Bf[9],  Bf[10], Bf[11]);
    *(float4*)&vd1[4] = make_float4(Bf[12], Bf[13], Bf[14], Bf[15]);
  }
  __syncthreads();

  int cnt = 0;
  for (int m = 0; m < NW / 2; ++m) {
    const int k = 2 * m;
    const int par = m & 1;
    const float* v0 = vrow[par][0];
    const float* v1 = vrow[par][1];

    // ---- 2x2 pivot chain: one b64 + one b32 uniform read ----
    const int kpos = (k >> 3) * PAD + (k & 7);      // k even -> 8B-aligned
    const float2 p01 = *(const float2*)&v0[kpos];
    const float d0  = p01.x;
    const float u01 = p01.y;
    const float e1  = v1[kpos + 1];
    const float d0g = (fabsf(d0) < PIV_EPS) ? copysignf(PIV_EPS, d0) : d0;
    const float i0  = __builtin_amdgcn_rcpf(d0g);
    const float l10 = u01 * i0;
    const float d1  = e1 - l10 * u01;
    const float d1g = (fabsf(d1) < PIV_EPS) ? copysignf(PIV_EPS, d1) : d1;
    const float i1  = __builtin_amdgcn_rcpf(d1g);
    cnt += (d0 < 0.f) ? 1 : 0;
    cnt += (d1 < 0.f) ? 1 : 0;

    if (16 * w + 15 > k) {            // wave has live columns
      // row values: 4x b128 (16B-aligned, bank-group injective)
      const float4 ra0 = *(const float4*)&v0[rg * PAD + 0];
      const float4 ra1 = *(const float4*)&v0[rg * PAD + 4];
      const float4 rb0 = *(const float4*)&v1[rg * PAD + 0];
      const float4 rb1 = *(const float4*)&v1[rg * PAD + 4];
      // col values: 4x b128 uniform broadcasts (per half-wave)
      const float4 ca0 = *(const float4*)&v0[ch * PAD + 0];
      const float4 ca1 = *(const float4*)&v0[ch * PAD + 4];
      const float4 cb0 = *(const float4*)&v1[ch * PAD + 0];
      const float4 cb1 = *(const float4*)&v1[ch * PAD + 4];
      const float rv0[8] = {ra0.x, ra0.y, ra0.z, ra0.w, ra1.x, ra1.y, ra1.z, ra1.w};
      const float rv1[8] = {rb0.x, rb0.y, rb0.z, rb0.w, rb1.x, rb1.y, rb1.z, rb1.w};
      const float cv0[8] = {ca0.x, ca0.y, ca0.z, ca0.w, ca1.x, ca1.y, ca1.z, ca1.w};
      const float cv1[8] = {cb0.x, cb0.y, cb0.z, cb0.w, cb1.x, cb1.y, cb1.z, cb1.w};

      // factors: f0 = -L0[r], f1 = -L1[r]; folded g0 = f0 - l10*f1
      float g0[8], f1[8];
#pragma unroll
      for (int i = 0; i < 8; ++i) {
        const int r = r0 + i;
        const float f0 = (r > k)     ? -rv0[i] * i0 : 0.f;
        const float v1p = rv1[i] - l10 * rv0[i];   // updated column k+1 at row r
        f1[i] = (r > k + 1) ? -v1p * i1 : 0.f;
        g0[i] = f0 - l10 * f1[i];
      }
      // rank-2 update: B += g0*cv0^T + f1*cv1^T
#pragma unroll
      for (int i = 0; i < 8; ++i) {
#pragma unroll
        for (int j = 0; j < 8; ++j) {
          Bf[i*8+j] = fmaf(g0[i], cv0[j], fmaf(f1[i], cv1[j], Bf[i*8+j]));
        }
      }
      // dump rows k+2, k+3 (same owner row-group since k is even)
      const int nr = k + 2;
      if (nr < NW && rg == (nr >> 3)) {
        float* vd0 = &vrow[par ^ 1][0][ch * PAD];
        float* vd1 = &vrow[par ^ 1][1][ch * PAD];
        switch (nr & 7) {
          case 0:
            *(float4*)&vd0[0] = make_float4(Bf[0],  Bf[1],  Bf[2],  Bf[3]);
            *(float4*)&vd0[4] = make_float4(Bf[4],  Bf[5],  Bf[6],  Bf[7]);
            *(float4*)&vd1[0] = make_float4(Bf[8],  Bf[9],  Bf[10], Bf[11]);
            *(float4*)&vd1[4] = make_float4(Bf[12], Bf[13], Bf[14], Bf[15]);
            break;
          case 2:
            *(float4*)&vd0[0] = make_float4(Bf[16], Bf[17], Bf[18], Bf[19]);
            *(float4*)&vd0[4] = make_float4(Bf[20], Bf[21], Bf[22], Bf[23]);
            *(float4*)&vd1[0] = make_float4(Bf[24], Bf[25], Bf[26], Bf[27]);
            *(float4*)&vd1[4] = make_float4(Bf[28], Bf[29], Bf[30], Bf[31]);
            break;
          case 4:
            *(float4*)&vd0[0] = make_float4(Bf[32], Bf[33], Bf[34], Bf[35]);
            *(float4*)&vd0[4] = make_float4(Bf[36], Bf[37], Bf[38], Bf[39]);
            *(float4*)&vd1[0] = make_float4(Bf[40], Bf[41], Bf[42], Bf[43]);
            *(float4*)&vd1[4] = make_float4(Bf[44], Bf[45], Bf[46], Bf[47]);
            break;
          default:  // case 6
            *(float4*)&vd0[0] = make_float4(Bf[48], Bf[49], Bf[50], Bf[51]);
            *(float4*)&vd0[4] = make_float4(Bf[52], Bf[53], Bf[54], Bf[55]);
            *(float4*)&vd1[0] = make_float4(Bf[56], Bf[57], Bf[58], Bf[59]);
            *(float4*)&vd1[4] = make_float4(Bf[60], Bf[61], Bf[62], Bf[63]);
            break;
        }
      }
    }
    __syncthreads();
  }

  if (t == 0) counts[mat * NS + s] = cnt;
}

// ---------------- gather: bin each sorted eigenvalue from inertia counts ----------------
__global__ void gather_kernel(const int* __restrict__ counts,
                              const unsigned int* __restrict__ rsmax,
                              float* __restrict__ sigw) {
  const int mat = blockIdx.x;   // 10
  const int j = threadIdx.x;    // 256, ascending eigenvalue index
  __shared__ int cs[NS];
  if (j < NS) cs[j] = counts[mat * NS + j];
  __syncthreads();
  const float h = sqrtf(__uint_as_float(rsmax[mat])) * (1.f / NS);
  int cmax = 0;
  int sstar = NS - 1;
  bool found = false;
  for (int s = 0; s < NS; ++s) {
    cmax = max(cmax, cs[s]);              // enforce monotone counts
    if (!found && cmax > j) { sstar = s; found = true; }
  }
  // lambda_j in [mu_{s*-1}, mu_{s*}) -> sigma in [s*h, (s*+1)h)
  sigw[mat * NW + (255 - j)] = (sstar + 0.5f) * h;   // descending order
}

// ---------------- mean over blocks, broadcast over batch ----------------
__global__ void sig_avg_kernel(const float* __restrict__ sig, float* __restrict__ out_all) {
  const int b = blockIdx.x;   // 256
  const int j = threadIdx.x;  // 256
  float s = 0.f;
#pragma unroll
  for (int k = 0; k < NDEPTH; ++k) s += sig[k * NW + j];
  out_all[b * NW + j] = s * 0.1f;
}

extern "C" void kernel_launch(void* const* d_in, const int* in_sizes, int n_in,
                              void* d_out, int out_size, void* d_ws, size_t ws_size,
                              hipStream_t stream) {
  const float* x  = (const float*)d_in[0];
  const float* W1 = (const float*)d_in[1];
  const float* b1 = (const float*)d_in[2];
  const float* Wb = (const float*)d_in[3];
  const float* bb = (const float*)d_in[4];
  const float* Wl = (const float*)d_in[5];
  const float* bl = (const float*)d_in[6];
  float* out = (float*)d_out;               // 2560 + 65536

  float* ws = (float*)d_ws;
  float* Ball   = ws;                            // 10*65536 = 655360 floats
  float* sigw   = ws + 655360;                   // 2560 floats
  unsigned int* rsmaxW = (unsigned int*)(ws + 657920);  // 10 uints
  int*   counts = (int*)(ws + 657936);           // 10*NS ints

  hipMemsetAsync(rsmaxW, 0, NDEPTH * sizeof(unsigned int), stream);
  bmat_kernel<<<dim3(NDEPTH * 32), dim3(256), 0, stream>>>(Wb, Ball, rsmaxW);
  forward_kernel<<<dim3(256), dim3(256), 0, stream>>>(x, W1, b1, Wb, bb, Wl, bl, out);
  ldl_kernel<<<dim3(NS, NDEPTH), dim3(1024), 0, stream>>>(Ball, rsmaxW, counts);
  gather_kernel<<<dim3(NDEPTH), dim3(256), 0, stream>>>(counts, rsmaxW, sigw);
  sig_avg_kernel<<<dim3(256), dim3(256), 0, stream>>>(sigw, out + 2560);
}

// Round 12
// 286.243 us; speedup vs baseline: 14.1710x; 14.1710x over previous
//
#include <hip/hip_runtime.h>
#include <hip/hip_bf16.h>

#define NW 256
#define NDEPTH 10
#define NS 25           // shifts per matrix: 250 WGs = exactly ONE round at 1 WG/CU
#define PAD 12          // stride 48B: 16B-aligned rows, bank-group 3rg%8 injective
#define PIV_EPS 1e-6f   // LDL tiny-pivot guard

// ---------------- fused forward: first fc + 10 residual blocks + last fc ----------------
__global__ __launch_bounds__(256) void forward_kernel(
    const float* __restrict__ x, const float* __restrict__ W1, const float* __restrict__ b1,
    const float* __restrict__ Wb, const float* __restrict__ bb,
    const float* __restrict__ Wl, const float* __restrict__ bl,
    float* __restrict__ out) {
  const int b = blockIdx.x;
  const int o = threadIdx.x;
  __shared__ __align__(16) float xs[784];
  __shared__ __align__(16) float ybuf[2][NW];

  for (int k = o; k < 784; k += 256) xs[k] = x[(size_t)b * 784 + k];
  __syncthreads();

  {
    const float* w1r = W1 + (size_t)o * 784;
    float s = b1[o];
    for (int k = 0; k < 784; k += 4) {
      float4 w = *(const float4*)(w1r + k);
      float4 xv = *(const float4*)(&xs[k]);
      s += w.x * xv.x + w.y * xv.y + w.z * xv.z + w.w * xv.w;
    }
    ybuf[0][o] = fmaxf(s, 0.f);
  }
  __syncthreads();

  int cur = 0;
  for (int d = 0; d < NDEPTH; ++d) {
    const float* wr = Wb + (size_t)d * NW * NW + (size_t)o * NW;
    const float* yc = ybuf[cur];
    float acc = bb[d * NW + o];
#pragma unroll 8
    for (int k = 0; k < NW; k += 4) {
      float4 w = *(const float4*)(wr + k);
      float4 yv = *(const float4*)(&yc[k]);
      acc += w.x * yv.x + w.y * yv.y + w.z * yv.z + w.w * yv.w;
    }
    float ynew = fmaxf(acc, 0.f) + yc[o];
    ybuf[cur ^ 1][o] = ynew;
    __syncthreads();
    cur ^= 1;
  }

  if (o < 10) {
    const float* wr = Wl + o * NW;
    const float* yc = ybuf[cur];
    float acc = bl[o];
    for (int k = 0; k < NW; k += 4) {
      float4 w = *(const float4*)(wr + k);
      float4 yv = *(const float4*)(&yc[k]);
      acc += w.x * yv.x + w.y * yv.y + w.z * yv.z + w.w * yv.w;
    }
    out[b * 10 + o] = acc;
  }
}

// ---------------- B = (I+W)^T (I+W) for all 10 blocks + fused max-abs-rowsum ----------------
__global__ void bmat_kernel(const float* __restrict__ Wb, float* __restrict__ Ball,
                            unsigned int* __restrict__ rsmax) {
  const int blk = blockIdx.x;        // 10 * 32
  const int k   = blk >> 5;
  const int r0  = (blk & 31) << 3;   // 8 rows per block
  const int c   = threadIdx.x;       // 256
  const float* W = Wb + (size_t)k * NW * NW;
  float acc[8] = {0.f,0.f,0.f,0.f,0.f,0.f,0.f,0.f};
  for (int j = 0; j < NW; ++j) {
    const float wc = W[j * NW + c];
#pragma unroll
    for (int rr = 0; rr < 8; ++rr) acc[rr] += wc * W[j * NW + r0 + rr];
  }
  float a[8];
#pragma unroll
  for (int rr = 0; rr < 8; ++rr) {
    const int r = r0 + rr;
    const float s = acc[rr] + W[c * NW + r] + W[r * NW + c] + ((r == c) ? 1.f : 0.f);
    Ball[(size_t)k * NW * NW + r * NW + c] = s;
    a[rr] = fabsf(s);
  }
  __shared__ float wsum[4][8];
#pragma unroll
  for (int off = 32; off; off >>= 1) {
#pragma unroll
    for (int rr = 0; rr < 8; ++rr) a[rr] += __shfl_down(a[rr], off);
  }
  if ((c & 63) == 0) {
#pragma unroll
    for (int rr = 0; rr < 8; ++rr) wsum[c >> 6][rr] = a[rr];
  }
  __syncthreads();
  if (c == 0) {
    float mx = 0.f;
#pragma unroll
    for (int rr = 0; rr < 8; ++rr) {
      const float s = wsum[0][rr] + wsum[1][rr] + wsum[2][rr] + wsum[3][rr];
      mx = fmaxf(mx, s);
    }
    atomicMax(&rsmax[k], __float_as_uint(mx));   // positive floats: uint order == float order
  }
}

// ---------------- LDL inertia kernel v7: rank-2, b128 LDS, (1024,4) ----------------
// counts[mat*NS + s] = #negative pivots of LDL^T(B - mu_s I) = #{lambda < mu_s}.
// launch_bounds (1024,4): 128-reg unified budget so the 8x8 tile stays on-chip
// (R11 ERRATum: (1024,8) capped at 64 regs -> tile spilled to scratch, 12x slower).
__global__ __launch_bounds__(1024, 4) void ldl_kernel(const float* __restrict__ Ball,
                                                      const unsigned int* __restrict__ rsmax,
                                                      int* __restrict__ counts) {
  const int s   = blockIdx.x;     // shift index 0..NS-1
  const int mat = blockIdx.y;     // 0..9
  const int t = threadIdx.x;      // 0..1023
  const int l = t & 63;
  const int w = t >> 6;              // wave 0..15
  const int rg = l & 31;             // row group: rows [8rg, 8rg+8)
  const int ch = 2 * w + (l >> 5);   // col chunk: cols [8ch, 8ch+8)
  const int r0 = rg << 3;

  __shared__ __align__(16) float vrow[2][2][32 * PAD];   // [m-parity][row k+0/k+1]

  const float h = sqrtf(__uint_as_float(rsmax[mat])) * (1.f / NS);
  const float sg = (s + 1) * h;
  const float mu = sg * sg;

  float Bf[64];   // row r0+i, col c0+j at Bf[i*8+j]
  {
    const float* src = Ball + (size_t)mat * NW * NW + (size_t)r0 * NW + (ch << 3);
#pragma unroll
    for (int i = 0; i < 8; ++i) {
      const float4 a = *(const float4*)(src + i * NW);
      const float4 b = *(const float4*)(src + i * NW + 4);
      Bf[i*8+0] = a.x; Bf[i*8+1] = a.y; Bf[i*8+2] = a.z; Bf[i*8+3] = a.w;
      Bf[i*8+4] = b.x; Bf[i*8+5] = b.y; Bf[i*8+6] = b.z; Bf[i*8+7] = b.w;
    }
  }
  if (rg == ch) {
#pragma unroll
    for (int i = 0; i < 8; ++i) Bf[i*8+i] -= mu;
  }

  // initial dump: rows 0 and 1 (= columns 0,1), parity 0
  if (rg == 0) {
    float* vd0 = &vrow[0][0][ch * PAD];
    float* vd1 = &vrow[0][1][ch * PAD];
    *(float4*)&vd0[0] = make_float4(Bf[0],  Bf[1],  Bf[2],  Bf[3]);
    *(float4*)&vd0[4] = make_float4(Bf[4],  Bf[5],  Bf[6],  Bf[7]);
    *(float4*)&vd1[0] = make_float4(Bf[8],  Bf[9],  Bf[10], Bf[11]);
    *(float4*)&vd1[4] = make_float4(Bf[12], Bf[13], Bf[14], Bf[15]);
  }
  __syncthreads();

  int cnt = 0;
  for (int m = 0; m < NW / 2; ++m) {
    const int k = 2 * m;
    const int par = m & 1;
    const float* v0 = vrow[par][0];
    const float* v1 = vrow[par][1];

    // ---- 2x2 pivot chain: one b64 + one b32 uniform read ----
    const int kpos = (k >> 3) * PAD + (k & 7);      // k even -> 8B-aligned
    const float2 p01 = *(const float2*)&v0[kpos];
    const float d0  = p01.x;
    const float u01 = p01.y;
    const float e1  = v1[kpos + 1];
    const float d0g = (fabsf(d0) < PIV_EPS) ? copysignf(PIV_EPS, d0) : d0;
    const float i0  = __builtin_amdgcn_rcpf(d0g);
    const float l10 = u01 * i0;
    const float d1  = e1 - l10 * u01;
    const float d1g = (fabsf(d1) < PIV_EPS) ? copysignf(PIV_EPS, d1) : d1;
    const float i1  = __builtin_amdgcn_rcpf(d1g);
    cnt += (d0 < 0.f) ? 1 : 0;
    cnt += (d1 < 0.f) ? 1 : 0;

    if (16 * w + 15 > k) {            // wave has live columns
      const float4 ra0 = *(const float4*)&v0[rg * PAD + 0];
      const float4 ra1 = *(const float4*)&v0[rg * PAD + 4];
      const float4 rb0 = *(const float4*)&v1[rg * PAD + 0];
      const float4 rb1 = *(const float4*)&v1[rg * PAD + 4];
      const float4 ca0 = *(const float4*)&v0[ch * PAD + 0];
      const float4 ca1 = *(const float4*)&v0[ch * PAD + 4];
      const float4 cb0 = *(const float4*)&v1[ch * PAD + 0];
      const float4 cb1 = *(const float4*)&v1[ch * PAD + 4];
      const float rv0[8] = {ra0.x, ra0.y, ra0.z, ra0.w, ra1.x, ra1.y, ra1.z, ra1.w};
      const float rv1[8] = {rb0.x, rb0.y, rb0.z, rb0.w, rb1.x, rb1.y, rb1.z, rb1.w};
      const float cv0[8] = {ca0.x, ca0.y, ca0.z, ca0.w, ca1.x, ca1.y, ca1.z, ca1.w};
      const float cv1[8] = {cb0.x, cb0.y, cb0.z, cb0.w, cb1.x, cb1.y, cb1.z, cb1.w};

      float g0[8], f1[8];
#pragma unroll
      for (int i = 0; i < 8; ++i) {
        const int r = r0 + i;
        const float f0 = (r > k)     ? -rv0[i] * i0 : 0.f;
        const float v1p = rv1[i] - l10 * rv0[i];
        f1[i] = (r > k + 1) ? -v1p * i1 : 0.f;
        g0[i] = f0 - l10 * f1[i];
      }
#pragma unroll
      for (int i = 0; i < 8; ++i) {
#pragma unroll
        for (int j = 0; j < 8; ++j) {
          Bf[i*8+j] = fmaf(g0[i], cv0[j], fmaf(f1[i], cv1[j], Bf[i*8+j]));
        }
      }
      const int nr = k + 2;
      if (nr < NW && rg == (nr >> 3)) {
        float* vd0 = &vrow[par ^ 1][0][ch * PAD];
        float* vd1 = &vrow[par ^ 1][1][ch * PAD];
        switch (nr & 7) {
          case 0:
            *(float4*)&vd0[0] = make_float4(Bf[0],  Bf[1],  Bf[2],  Bf[3]);
            *(float4*)&vd0[4] = make_float4(Bf[4],  Bf[5],  Bf[6],  Bf[7]);
            *(float4*)&vd1[0] = make_float4(Bf[8],  Bf[9],  Bf[10], Bf[11]);
            *(float4*)&vd1[4] = make_float4(Bf[12], Bf[13], Bf[14], Bf[15]);
            break;
          case 2:
            *(float4*)&vd0[0] = make_float4(Bf[16], Bf[17], Bf[18], Bf[19]);
            *(float4*)&vd0[4] = make_float4(Bf[20], Bf[21], Bf[22], Bf[23]);
            *(float4*)&vd1[0] = make_float4(Bf[24], Bf[25], Bf[26], Bf[27]);
            *(float4*)&vd1[4] = make_float4(Bf[28], Bf[29], Bf[30], Bf[31]);
            break;
          case 4:
            *(float4*)&vd0[0] = make_float4(Bf[32], Bf[33], Bf[34], Bf[35]);
            *(float4*)&vd0[4] = make_float4(Bf[36], Bf[37], Bf[38], Bf[39]);
            *(float4*)&vd1[0] = make_float4(Bf[40], Bf[41], Bf[42], Bf[43]);
            *(float4*)&vd1[4] = make_float4(Bf[44], Bf[45], Bf[46], Bf[47]);
            break;
          default:  // case 6
            *(float4*)&vd0[0] = make_float4(Bf[48], Bf[49], Bf[50], Bf[51]);
            *(float4*)&vd0[4] = make_float4(Bf[52], Bf[53], Bf[54], Bf[55]);
            *(float4*)&vd1[0] = make_float4(Bf[56], Bf[57], Bf[58], Bf[59]);
            *(float4*)&vd1[4] = make_float4(Bf[60], Bf[61], Bf[62], Bf[63]);
            break;
        }
      }
    }
    __syncthreads();
  }

  if (t == 0) counts[mat * NS + s] = cnt;
}

// ---------------- gather: bin each sorted eigenvalue from inertia counts ----------------
__global__ void gather_kernel(const int* __restrict__ counts,
                              const unsigned int* __restrict__ rsmax,
                              float* __restrict__ sigw) {
  const int mat = blockIdx.x;   // 10
  const int j = threadIdx.x;    // 256, ascending eigenvalue index
  __shared__ int cs[NS];
  if (j < NS) cs[j] = counts[mat * NS + j];
  __syncthreads();
  const float h = sqrtf(__uint_as_float(rsmax[mat])) * (1.f / NS);
  int cmax = 0;
  int sstar = NS - 1;
  bool found = false;
  for (int s = 0; s < NS; ++s) {
    cmax = max(cmax, cs[s]);              // enforce monotone counts
    if (!found && cmax > j) { sstar = s; found = true; }
  }
  sigw[mat * NW + (255 - j)] = (sstar + 0.5f) * h;   // descending order
}

// ---------------- mean over blocks, broadcast over batch ----------------
__global__ void sig_avg_kernel(const float* __restrict__ sig, float* __restrict__ out_all) {
  const int b = blockIdx.x;   // 256
  const int j = threadIdx.x;  // 256
  float s = 0.f;
#pragma unroll
  for (int k = 0; k < NDEPTH; ++k) s += sig[k * NW + j];
  out_all[b * NW + j] = s * 0.1f;
}

extern "C" void kernel_launch(void* const* d_in, const int* in_sizes, int n_in,
                              void* d_out, int out_size, void* d_ws, size_t ws_size,
                              hipStream_t stream) {
  const float* x  = (const float*)d_in[0];
  const float* W1 = (const float*)d_in[1];
  const float* b1 = (const float*)d_in[2];
  const float* Wb = (const float*)d_in[3];
  const float* bb = (const float*)d_in[4];
  const float* Wl = (const float*)d_in[5];
  const float* bl = (const float*)d_in[6];
  float* out = (float*)d_out;               // 2560 + 65536

  float* ws = (float*)d_ws;
  float* Ball   = ws;                            // 10*65536 = 655360 floats
  float* sigw   = ws + 655360;                   // 2560 floats
  unsigned int* rsmaxW = (unsigned int*)(ws + 657920);  // 10 uints
  int*   counts = (int*)(ws + 657936);           // 10*NS ints

  hipMemsetAsync(rsmaxW, 0, NDEPTH * sizeof(unsigned int), stream);
  bmat_kernel<<<dim3(NDEPTH * 32), dim3(256), 0, stream>>>(Wb, Ball, rsmaxW);
  forward_kernel<<<dim3(256), dim3(256), 0, stream>>>(x, W1, b1, Wb, bb, Wl, bl, out);
  ldl_kernel<<<dim3(NS, NDEPTH), dim3(1024), 0, stream>>>(Ball, rsmaxW, counts);
  gather_kernel<<<dim3(NDEPTH), dim3(256), 0, stream>>>(counts, rsmaxW, sigw);
  sig_avg_kernel<<<dim3(256), dim3(256), 0, stream>>>(sigw, out + 2560);
}